// Round 4
// baseline (533.440 us; speedup 1.0000x reference)
//
#include <hip/hip_runtime.h>

#define B_ 1024
#define T_ 200
#define H_ 128

typedef __attribute__((ext_vector_type(8))) short short8;
typedef __attribute__((ext_vector_type(4))) float f32x4;

#define MFMA(a, b, c) __builtin_amdgcn_mfma_f32_16x16x32_bf16((a), (b), (c), 0, 0, 0)

static __device__ __forceinline__ short f2bf(float f) {
  unsigned u = __float_as_uint(f);
  u += 0x7fffu + ((u >> 16) & 1u);  // RNE
  return (short)(u >> 16);
}
static __device__ __forceinline__ float bf2f(short s) {
  return __uint_as_float(((unsigned)(unsigned short)s) << 16);
}
static __device__ __forceinline__ unsigned pack2bf_rne(float a, float b) {
  unsigned ua = __float_as_uint(a);
  ua += 0x7fffu + ((ua >> 16) & 1u);
  unsigned ub = __float_as_uint(b);
  ub += 0x7fffu + ((ub >> 16) & 1u);
  return (ua >> 16) | (ub & 0xFFFF0000u);
}
static __device__ __forceinline__ float rcp_f(float x) { return __builtin_amdgcn_rcpf(x); }
// LDS-only barrier: does NOT drain vmcnt (global prefetches stay in flight)
static __device__ __forceinline__ void ck_barrier() {
  asm volatile("s_waitcnt lgkmcnt(0)\n\ts_barrier" ::: "memory");
}

// ---------------------------------------------------------------------------
// K_A proj v2: attention scores (2-pass split bf16: ahi*whi + ahi*wlo) +
// hist->bf16 repack into PLAIN row-major global layout (written straight from
// the prefetch registers). Depth-2 tile prefetch; ONE barrier per iter; score
// finalization pipelined one iter behind. Grid (13 t-chunks, 64 row-groups).
// ---------------------------------------------------------------------------
__global__ __launch_bounds__(512, 4) void proj_scores_kernel(
    const float* __restrict__ tgt, const float* __restrict__ hist,
    const float* __restrict__ Ww, const float* __restrict__ Wb,
    float* __restrict__ scores, short* __restrict__ histbf) {
  const int tc = blockIdx.x, bb = blockIdx.y;
  const int nt = (tc == 12) ? 8 : 16;
  const int t0 = tc * 16;
  const int tid = threadIdx.x;
  const int lane = tid & 63, w = tid >> 6;
  const int n = lane & 15, q = lane >> 4;

  __shared__ short tgt_hi[2][16 * 128];
  __shared__ float hist_f[2][16 * 132];
  __shared__ float sp[2][128];

  short8 whi[4], wlo[4];
  float wb;
  {
    const int o = w * 16 + n;
    wb = Wb[o];
#pragma unroll
    for (int ks = 0; ks < 4; ++ks) {
      const float* p = Ww + o * H_ + ks * 32 + q * 8;
      short8 h, l;
#pragma unroll
      for (int j = 0; j < 8; ++j) {
        float f = p[j];
        short hv16 = f2bf(f);
        h[j] = hv16;
        l[j] = f2bf(f - bf2f(hv16));
      }
      whi[ks] = h;
      wlo[ks] = l;
    }
  }

  const int sm = tid >> 5, cs = tid & 31;
  const int gran = cs >> 1, half = cs & 1;
  const int spos16 = sm * 128 + (gran ^ (sm & 7)) * 8 + half * 4;
  const int sposf = sm * 132 + cs * 4;
  const int row = bb * 16 + sm;
  const float* hsrc = hist + (size_t)row * T_ * H_ + cs * 4;
  const float* tsrc = tgt + (size_t)row * T_ * H_ + cs * 4;
  short* hbdst = histbf ? (histbf + (size_t)row * T_ * H_ + cs * 4) : nullptr;

  // stage tile 0 (+ histbf for t0)
  {
    float4 h0 = *(const float4*)(hsrc + (size_t)t0 * H_);
    float4 t0v = *(const float4*)(tsrc + (size_t)t0 * H_);
    *(float4*)&hist_f[0][sposf] = h0;
    uint2 th;
    th.x = pack2bf_rne(t0v.x, t0v.y);
    th.y = pack2bf_rne(t0v.z, t0v.w);
    *(uint2*)&tgt_hi[0][spos16] = th;
    if (hbdst) {
      uint2 hh;
      hh.x = pack2bf_rne(h0.x, h0.y);
      hh.y = pack2bf_rne(h0.z, h0.w);
      *(uint2*)(hbdst + (size_t)t0 * H_) = hh;
    }
  }
  // depth-2 prefetch: slot (tl&1) is issued at iter tl for tile tl+2;
  // slot ((tl+1)&1) holds tile tl+1, staged at end of iter tl.
  float4 hv[2], tv[2];
  if (nt > 1) {
    hv[1] = *(const float4*)(hsrc + (size_t)(t0 + 1) * H_);
    tv[1] = *(const float4*)(tsrc + (size_t)(t0 + 1) * H_);
  }
  ck_barrier();

#pragma unroll 2
  for (int tl = 0; tl < nt; ++tl) {
    const int cur = tl & 1;
    // finalize previous t's score (writes from last iter, across one barrier)
    if (tl > 0 && tid < 16) {
      float s = 0.0f;
#pragma unroll
      for (int ww = 0; ww < 8; ++ww) s += sp[cur ^ 1][tid * 8 + ww];
      scores[(size_t)(bb * 16 + tid) * T_ + (t0 + tl - 1)] = s;
    }
    // issue loads for tile tl+2
    if (tl + 2 < nt) {
      hv[cur] = *(const float4*)(hsrc + (size_t)(t0 + tl + 2) * H_);
      tv[cur] = *(const float4*)(tsrc + (size_t)(t0 + tl + 2) * H_);
    }
    // 2-pass split-bf16 MFMA
    f32x4 s1 = {0, 0, 0, 0}, s2 = {0, 0, 0, 0};
#pragma unroll
    for (int ks = 0; ks < 4; ++ks) {
      const int fp = n * 128 + ((ks * 4 + q) ^ (n & 7)) * 8;
      short8 ahi = *(short8*)&tgt_hi[cur][fp];
      s1 = MFMA(ahi, whi[ks], s1);
      s2 = MFMA(ahi, wlo[ks], s2);
    }
#pragma unroll
    for (int r = 0; r < 4; ++r) {
      const int m = q * 4 + r;
      float v = (s1[r] + s2[r] + wb) * hist_f[cur][m * 132 + w * 16 + n];
      v += __shfl_xor(v, 1);
      v += __shfl_xor(v, 2);
      v += __shfl_xor(v, 4);
      v += __shfl_xor(v, 8);
      if (n == 0) sp[cur][m * 8 + w] = v;
    }
    // stage tile tl+1 (loaded 2 iters ago -> vmcnt long since satisfied)
    if (tl + 1 < nt) {
      float4 hs = hv[cur ^ 1], ts = tv[cur ^ 1];
      *(float4*)&hist_f[cur ^ 1][sposf] = hs;
      uint2 th;
      th.x = pack2bf_rne(ts.x, ts.y);
      th.y = pack2bf_rne(ts.z, ts.w);
      *(uint2*)&tgt_hi[cur ^ 1][spos16] = th;
      if (hbdst) {
        uint2 hh;
        hh.x = pack2bf_rne(hs.x, hs.y);
        hh.y = pack2bf_rne(hs.z, hs.w);
        *(uint2*)(hbdst + (size_t)(t0 + tl + 1) * H_) = hh;
      }
    }
    ck_barrier();
  }
  if (tid < 16) {
    float s = 0.0f;
#pragma unroll
    for (int ww = 0; ww < 8; ++ww) s += sp[(nt - 1) & 1][tid * 8 + ww];
    scores[(size_t)(bb * 16 + tid) * T_ + (t0 + nt - 1)] = s;
  }
}

// ---------------------------------------------------------------------------
// K_B: softmax over T, in place. One block per batch row.
// ---------------------------------------------------------------------------
__global__ __launch_bounds__(256, 4) void softmax_kernel(float* __restrict__ att) {
  const int b = blockIdx.x, tid = threadIdx.x;
  const int lane = tid & 63, wave = tid >> 6;
  __shared__ float red[8];
  float v = (tid < T_) ? att[(size_t)b * T_ + tid] : -3.0e38f;
  float mx = v;
#pragma unroll
  for (int d = 1; d < 64; d <<= 1) mx = fmaxf(mx, __shfl_xor(mx, d));
  if (lane == 0) red[wave] = mx;
  __syncthreads();
  mx = fmaxf(fmaxf(red[0], red[1]), fmaxf(red[2], red[3]));
  float e = (tid < T_) ? __expf(v - mx) : 0.0f;
  float sm = e;
#pragma unroll
  for (int d = 1; d < 64; d <<= 1) sm += __shfl_xor(sm, d);
  if (lane == 0) red[4 + wave] = sm;
  __syncthreads();
  sm = red[4] + red[5] + red[6] + red[7];
  if (tid < T_) att[(size_t)b * T_ + tid] = e / sm;
}

// ---------------------------------------------------------------------------
// K_C scan v4: 256 blocks x 4 batch rows x 512 thr (8 waves, wave w = coltile
// w). Row-duplicated MFMA: A-frag row m holds real row (m&3); duplicate D rows
// are identical and ignored. x A-frags load DIRECT from plain bf16 histbf
// (L1 broadcasts), depth-2 reg prefetch across lgkm-only barriers. h LDS
// round-trip in 2.3 KB (pad-144 rows: <=2-way banks, free). One b16 write per
// lane (row = q). Gates rcp-based.
// ---------------------------------------------------------------------------
template <bool PK>
__global__ __launch_bounds__(512, 2) void scan4_kernel(
    const float* __restrict__ hist,
    const float* __restrict__ xu_w, const float* __restrict__ xu_b,
    const float* __restrict__ hu_w, const float* __restrict__ hu_b,
    const float* __restrict__ xr_w, const float* __restrict__ xr_b,
    const float* __restrict__ hr_w, const float* __restrict__ hr_b,
    const float* __restrict__ xg_w, const float* __restrict__ xg_b,
    const float* __restrict__ hg_w, const float* __restrict__ hg_b,
    const float* __restrict__ att, const short* __restrict__ histbf,
    float* __restrict__ h_out) {
  const int tid = threadIdx.x;
  const int lane = tid & 63, w = tid >> 6;
  const int n = lane & 15, q = lane >> 4;
  const int bb = blockIdx.x, r0 = bb * 4;
  const int o = w * 16 + n;

  __shared__ short hbuf[2][4 * 144];  // rows padded to 144 shorts (288 B)

  short8 wf[6][4];  // 0=xu 1=hu 2=xr 3=hr 4=xg 5=hg
  {
    const float* Wm[6] = {xu_w, hu_w, xr_w, hr_w, xg_w, hg_w};
#pragma unroll
    for (int M = 0; M < 6; ++M)
#pragma unroll
      for (int ks = 0; ks < 4; ++ks) {
        const float* p = Wm[M] + o * H_ + ks * 32 + q * 8;
        short8 v;
#pragma unroll
        for (int j = 0; j < 8; ++j) v[j] = f2bf(p[j]);
        wf[M][ks] = v;
      }
  }
  const float bu = xu_b[o] + hu_b[o];
  const float br_ = xr_b[o] + hr_b[o];
  const float bxg = xg_b[o], bhg = hg_b[o];

  for (int i = tid; i < 2 * 4 * 144; i += 512) ((short*)hbuf)[i] = 0;

  const int xrow = r0 + (n & 3);
  typedef union { uint4 u; short8 s; } frag_u;
  frag_u xp[2][4];
  float4 xf0[2][4], xf1[2][4];
  const short* xb = PK ? (histbf + (size_t)xrow * T_ * H_ + q * 8) : nullptr;
  const float* xf = hist + (size_t)xrow * T_ * H_ + q * 8;
  if constexpr (PK) {
#pragma unroll
    for (int s = 0; s < 2; ++s)
#pragma unroll
      for (int ks = 0; ks < 4; ++ks)
        xp[s][ks].u = *(const uint4*)(xb + (size_t)s * H_ + ks * 32);
  } else {
#pragma unroll
    for (int s = 0; s < 2; ++s)
#pragma unroll
      for (int ks = 0; ks < 4; ++ks) {
        xf0[s][ks] = *(const float4*)(xf + (size_t)s * H_ + ks * 32);
        xf1[s][ks] = *(const float4*)(xf + (size_t)s * H_ + ks * 32 + 4);
      }
  }

  float ap[2][4];
#pragma unroll
  for (int s = 0; s < 2; ++s)
#pragma unroll
    for (int r = 0; r < 4; ++r) ap[s][r] = att[(size_t)(r0 + r) * T_ + s];

  float hreg[4] = {0.0f, 0.0f, 0.0f, 0.0f};
  ck_barrier();

#pragma unroll 2
  for (int t = 0; t < T_; ++t) {
    const int cur = t & 1, nxt = cur ^ 1;
    short8 ha[4];
#pragma unroll
    for (int ks = 0; ks < 4; ++ks)
      ha[ks] = *(const short8*)&hbuf[cur][(n & 3) * 144 + ks * 32 + q * 8];
    short8 xa[4];
    if constexpr (PK) {
#pragma unroll
      for (int ks = 0; ks < 4; ++ks) xa[ks] = xp[cur][ks].s;
    } else {
#pragma unroll
      for (int ks = 0; ks < 4; ++ks) {
        frag_u t_;
        float4 a = xf0[cur][ks], b = xf1[cur][ks];
        t_.u.x = pack2bf_rne(a.x, a.y);
        t_.u.y = pack2bf_rne(a.z, a.w);
        t_.u.z = pack2bf_rne(b.x, b.y);
        t_.u.w = pack2bf_rne(b.z, b.w);
        xa[ks] = t_.s;
      }
    }
    f32x4 axu = {0, 0, 0, 0}, ahu = {0, 0, 0, 0}, axr = {0, 0, 0, 0},
          ahr = {0, 0, 0, 0}, axg = {0, 0, 0, 0}, ahg = {0, 0, 0, 0};
#pragma unroll
    for (int ks = 0; ks < 4; ++ks) {
      axu = MFMA(xa[ks], wf[0][ks], axu);
      ahu = MFMA(ha[ks], wf[1][ks], ahu);
      axr = MFMA(xa[ks], wf[2][ks], axr);
      ahr = MFMA(ha[ks], wf[3][ks], ahr);
      axg = MFMA(xa[ks], wf[4][ks], axg);
      ahg = MFMA(ha[ks], wf[5][ks], ahg);
    }
    // prefetch t+2 (survives the lgkm-only barrier)
    const int tp = (t + 2 < T_) ? t + 2 : T_ - 1;
    if constexpr (PK) {
#pragma unroll
      for (int ks = 0; ks < 4; ++ks)
        xp[cur][ks].u = *(const uint4*)(xb + (size_t)tp * H_ + ks * 32);
    } else {
#pragma unroll
      for (int ks = 0; ks < 4; ++ks) {
        xf0[cur][ks] = *(const float4*)(xf + (size_t)tp * H_ + ks * 32);
        xf1[cur][ks] = *(const float4*)(xf + (size_t)tp * H_ + ks * 32 + 4);
      }
    }
    float at_c[4];
#pragma unroll
    for (int r = 0; r < 4; ++r) {
      at_c[r] = ap[cur][r];
      ap[cur][r] = att[(size_t)(r0 + r) * T_ + tp];
    }
    // gates (identical across quads by construction)
#pragma unroll
    for (int r = 0; r < 4; ++r) {
      const float su = axu[r] + ahu[r] + bu;
      const float u = at_c[r] * rcp_f(1.0f + __expf(-su));
      const float sr = axr[r] + ahr[r] + br_;
      const float rr = rcp_f(1.0f + __expf(-sr));
      const float sg = (axg[r] + bxg) + rr * (ahg[r] + bhg);
      const float g = 2.0f * rcp_f(1.0f + __expf(-2.0f * sg)) - 1.0f;
      hreg[r] = hreg[r] + u * (g - hreg[r]);
    }
    // write back row q (one b16 per lane)
    const float hsel = (q & 2) ? ((q & 1) ? hreg[3] : hreg[2])
                               : ((q & 1) ? hreg[1] : hreg[0]);
    hbuf[nxt][q * 144 + o] = (short)(__float_as_uint(hsel) >> 16);
    if (t == T_ - 1) h_out[(size_t)(r0 + q) * H_ + o] = hsel;
    ck_barrier();
  }
}

// ---------------------------------------------------------------------------
// K_D: out = [h | targets[:,0]] @ ln2_w^T + ln2_b (fp32)
// ---------------------------------------------------------------------------
__global__ __launch_bounds__(256, 4) void final_kernel(
    const float* __restrict__ tgt, const float* __restrict__ hfin,
    const float* __restrict__ w, const float* __restrict__ bias,
    float* __restrict__ out) {
  const int b = blockIdx.x, tid = threadIdx.x;
  const int o = tid >> 1, half = tid & 1;
  const float* src = half ? (tgt + (size_t)b * (T_ * H_)) : (hfin + (size_t)b * H_);
  const float* wrow = w + o * 256 + half * 128;
  float acc = 0.0f;
#pragma unroll 8
  for (int k = 0; k < 128; k += 4) {
    float4 sv = *(const float4*)(src + k);
    float4 wv = *(const float4*)(wrow + k);
    acc += sv.x * wv.x + sv.y * wv.y + sv.z * wv.z + sv.w * wv.w;
  }
  acc += __shfl_xor(acc, 1);
  if (half == 0) out[(size_t)b * H_ + o] = acc + bias[o];
}

extern "C" void kernel_launch(void* const* d_in, const int* in_sizes, int n_in,
                              void* d_out, int out_size, void* d_ws, size_t ws_size,
                              hipStream_t stream) {
  const float* targets = (const float*)d_in[0];
  const float* history = (const float*)d_in[1];
  const float* W_w = (const float*)d_in[2];
  const float* W_b = (const float*)d_in[3];
  const float* xu_w = (const float*)d_in[4];
  const float* xu_b = (const float*)d_in[5];
  const float* hu_w = (const float*)d_in[6];
  const float* hu_b = (const float*)d_in[7];
  const float* xr_w = (const float*)d_in[8];
  const float* xr_b = (const float*)d_in[9];
  const float* hr_w = (const float*)d_in[10];
  const float* hr_b = (const float*)d_in[11];
  const float* xg_w = (const float*)d_in[12];
  const float* xg_b = (const float*)d_in[13];
  const float* hg_w = (const float*)d_in[14];
  const float* hg_b = (const float*)d_in[15];
  const float* ln2_w = (const float*)d_in[16];
  const float* ln2_b = (const float*)d_in[17];
  float* out = (float*)d_out;

  float* att = (float*)d_ws;            // [B,T] f32
  float* hfin = att + (size_t)B_ * T_;  // [B,H] f32
  const size_t fixed = (size_t)B_ * T_ * 4 + (size_t)B_ * H_ * 4;
  const size_t histbf_bytes = (size_t)B_ * T_ * H_ * 2;  // 52.4 MB, plain [b][t][k] bf16
  short* histbf = (ws_size >= fixed + histbf_bytes)
                      ? (short*)((char*)d_ws + fixed)
                      : nullptr;

  proj_scores_kernel<<<dim3(13, 64), dim3(512), 0, stream>>>(
      targets, history, W_w, W_b, att, histbf);
  softmax_kernel<<<dim3(B_), dim3(256), 0, stream>>>(att);
  if (histbf) {
    scan4_kernel<true><<<dim3(B_ / 4), dim3(512), 0, stream>>>(
        history, xu_w, xu_b, hu_w, hu_b, xr_w, xr_b, hr_w, hr_b,
        xg_w, xg_b, hg_w, hg_b, att, histbf, hfin);
  } else {
    scan4_kernel<false><<<dim3(B_ / 4), dim3(512), 0, stream>>>(
        history, xu_w, xu_b, hu_w, hu_b, xr_w, xr_b, hr_w, hr_b,
        xg_w, xg_b, hg_w, hg_b, att, histbf, hfin);
  }
  final_kernel<<<dim3(B_), dim3(256), 0, stream>>>(targets, hfin, ln2_w, ln2_b, out);
}